// Round 1
// baseline (573.513 us; speedup 1.0000x reference)
//
#include <hip/hip_runtime.h>
#include <hip/hip_bf16.h>

// Problem constants (B=1)
#define N_TOK 8192
#define C_DIM 512
#define NH 8
#define DH 64
#define KCLUST 4
#define TPF 512
#define TOPK 204
#define MPC 2048   // tokens (queries) per cluster

// Workspace layout (float offsets)
#define WS_Q      0
#define WS_K      4194304
#define WS_V      8388608
#define WS_XATTN  12582912
#define WS_QBAR   16777216              // 8*4*64 = 2048
#define WS_AGG    (WS_QBAR + 2048)      // 4*8192 = 32768
#define WS_ML     (WS_AGG + 32768)      // 32*2048*2 = 131072
#define WS_SCORES (WS_ML + 131072)      // 32*204*2048 = 13369344
#define WS_TOPK   (WS_SCORES + 13369344) // ints: 4*204

// ---------------------------------------------------------------------------
// Generic fp32 GEMM: out[m][j] = sum_c A[m][c]*B[j][c] + bias[j]
// A: [M][Kdim] row-major, B: [Jdim][Kdim] row-major (i.e. B^T layout).
// WRITE_QKV=1: scatter j -> (sel,h,d) into q/k/v [h][n][d] arrays at out base.
// ---------------------------------------------------------------------------
template <int WRITE_QKV>
__global__ __launch_bounds__(256) void gemm_bt(
    const float* __restrict__ A, const float* __restrict__ B,
    const float* __restrict__ bias, float* __restrict__ out,
    int M, int Jdim, int Kdim) {
  __shared__ float As[16][68];
  __shared__ float Bs[16][68];
  const int tx = threadIdx.x, ty = threadIdx.y;
  const int tid = ty * 16 + tx;
  const int m0 = blockIdx.y * 64;
  const int j0 = blockIdx.x * 64;

  float acc[4][4];
#pragma unroll
  for (int i = 0; i < 4; i++)
#pragma unroll
    for (int j = 0; j < 4; j++) acc[i][j] = 0.f;

  for (int k0 = 0; k0 < Kdim; k0 += 16) {
#pragma unroll
    for (int i = 0; i < 4; i++) {
      int l = tid + i * 256;
      int r = l >> 4, c = l & 15;
      As[c][r] = A[(long)(m0 + r) * Kdim + k0 + c];
      Bs[c][r] = B[(long)(j0 + r) * Kdim + k0 + c];
    }
    __syncthreads();
#pragma unroll
    for (int kk = 0; kk < 16; kk++) {
      float a0 = As[kk][ty * 4 + 0], a1 = As[kk][ty * 4 + 1];
      float a2 = As[kk][ty * 4 + 2], a3 = As[kk][ty * 4 + 3];
      float b0 = Bs[kk][tx * 4 + 0], b1 = Bs[kk][tx * 4 + 1];
      float b2 = Bs[kk][tx * 4 + 2], b3 = Bs[kk][tx * 4 + 3];
      acc[0][0] += a0 * b0; acc[0][1] += a0 * b1; acc[0][2] += a0 * b2; acc[0][3] += a0 * b3;
      acc[1][0] += a1 * b0; acc[1][1] += a1 * b1; acc[1][2] += a1 * b2; acc[1][3] += a1 * b3;
      acc[2][0] += a2 * b0; acc[2][1] += a2 * b1; acc[2][2] += a2 * b2; acc[2][3] += a2 * b3;
      acc[3][0] += a3 * b0; acc[3][1] += a3 * b1; acc[3][2] += a3 * b2; acc[3][3] += a3 * b3;
    }
    __syncthreads();
  }

#pragma unroll
  for (int i = 0; i < 4; i++) {
    int m = m0 + ty * 4 + i;
#pragma unroll
    for (int j = 0; j < 4; j++) {
      int jj = j0 + tx * 4 + j;
      float val = acc[i][j] + bias[jj];
      if (WRITE_QKV) {
        int sel = jj >> 9;         // 0=q 1=k 2=v
        int h = (jj >> 6) & 7;
        int d = jj & 63;
        out[(long)sel * (NH * N_TOK * DH) + ((long)h * N_TOK + m) * DH + d] = val;
      } else {
        out[(long)m * Jdim + jj] = val;
      }
    }
  }
}

// ---------------------------------------------------------------------------
// qbar[h][kk][d] = mean over 512 tokens at keyframe kk of q[h][tok][d]
// ---------------------------------------------------------------------------
__global__ void qbar_kernel(const float* __restrict__ q,
                            const int* __restrict__ keyframes,
                            float* __restrict__ qbar) {
  int h = blockIdx.x >> 2, kk = blockIdx.x & 3, d = threadIdx.x;
  int base_tok = keyframes[kk] * TPF;
  float acc = 0.f;
  for (int t = 0; t < TPF; t++)
    acc += q[((long)h * N_TOK + base_tok + t) * DH + d];
  qbar[(h * 4 + kk) * DH + d] = acc * (1.0f / TPF);
}

// ---------------------------------------------------------------------------
// agg[kk][n] = (scale/NH) * sum_h sum_d qbar[h][kk][d] * k[h][n][d]
// 4 waves per block, one n per wave.
// ---------------------------------------------------------------------------
__global__ __launch_bounds__(256) void agg_kernel(const float* __restrict__ k,
                                                  const float* __restrict__ qbar,
                                                  float* __restrict__ agg) {
  __shared__ float qb[NH * KCLUST * DH];  // 2048 floats
  int tid = threadIdx.x;
  for (int i = tid; i < NH * KCLUST * DH; i += 256) qb[i] = qbar[i];
  __syncthreads();
  int wave = tid >> 6, lane = tid & 63;
  int n = blockIdx.x * 4 + wave;
  float a0 = 0.f, a1 = 0.f, a2 = 0.f, a3 = 0.f;
#pragma unroll
  for (int h = 0; h < NH; h++) {
    float kv = k[((long)h * N_TOK + n) * DH + lane];
    a0 += kv * qb[(h * 4 + 0) * DH + lane];
    a1 += kv * qb[(h * 4 + 1) * DH + lane];
    a2 += kv * qb[(h * 4 + 2) * DH + lane];
    a3 += kv * qb[(h * 4 + 3) * DH + lane];
  }
#pragma unroll
  for (int off = 32; off >= 1; off >>= 1) {
    a0 += __shfl_xor(a0, off);
    a1 += __shfl_xor(a1, off);
    a2 += __shfl_xor(a2, off);
    a3 += __shfl_xor(a3, off);
  }
  const float f = 0.125f / 8.0f;  // scale / NH
  if (lane == 0) {
    agg[0 * N_TOK + n] = a0 * f;
    agg[1 * N_TOK + n] = a1 * f;
    agg[2 * N_TOK + n] = a2 * f;
    agg[3 * N_TOK + n] = a3 * f;
  }
}

// ---------------------------------------------------------------------------
// Deterministic top-204 per row of agg (4 rows x 8192). Radix select on
// sortable uint keys, then ordered collection (ties -> lowest index).
// One block per row, 256 threads.
// ---------------------------------------------------------------------------
__global__ __launch_bounds__(256) void topk_kernel(const float* __restrict__ agg,
                                                   int* __restrict__ topk) {
  __shared__ unsigned sk[N_TOK];
  __shared__ int cnt[256];
  __shared__ int scn[256];
  int kk = blockIdx.x;
  int tid = threadIdx.x;
  const float* row = agg + (long)kk * N_TOK;

  for (int i = tid; i < N_TOK; i += 256) {
    unsigned u = __float_as_uint(row[i]);
    sk[i] = (u & 0x80000000u) ? ~u : (u | 0x80000000u);
  }
  __syncthreads();

  unsigned prefix = 0;
  int remaining = TOPK;
  for (int b = 31; b >= 0; b--) {
    unsigned cand = (prefix | (1u << b)) >> b;
    int c = 0;
    for (int i = tid; i < N_TOK; i += 256) c += ((sk[i] >> b) == cand) ? 1 : 0;
    cnt[tid] = c;
    __syncthreads();
    for (int s = 128; s > 0; s >>= 1) {
      if (tid < s) cnt[tid] += cnt[tid + s];
      __syncthreads();
    }
    int total = cnt[0];
    __syncthreads();
    if (total >= remaining) prefix |= (1u << b);
    else remaining -= total;
  }
  unsigned kth = prefix;  // key value of the 204th largest

  int* out_row = topk + kk * TOPK;
  int base = tid * 32;

  // pass A: strictly greater
  int cA = 0;
  for (int i = 0; i < 32; i++) cA += (sk[base + i] > kth) ? 1 : 0;
  scn[tid] = cA;
  __syncthreads();
  for (int s = 1; s < 256; s <<= 1) {
    int add = (tid >= s) ? scn[tid - s] : 0;
    __syncthreads();
    scn[tid] += add;
    __syncthreads();
  }
  int exclA = scn[tid] - cA;
  int G = scn[255];
  __syncthreads();
  int p = exclA;
  for (int i = 0; i < 32; i++)
    if (sk[base + i] > kth) out_row[p++] = base + i;
  __syncthreads();

  // pass B: equal to kth, take lowest indices until full
  int cB = 0;
  for (int i = 0; i < 32; i++) cB += (sk[base + i] == kth) ? 1 : 0;
  scn[tid] = cB;
  __syncthreads();
  for (int s = 1; s < 256; s <<= 1) {
    int add = (tid >= s) ? scn[tid - s] : 0;
    __syncthreads();
    scn[tid] += add;
    __syncthreads();
  }
  int exclB = scn[tid] - cB;
  int pos = G + exclB;
  for (int i = 0; i < 32; i++) {
    if (sk[base + i] == kth) {
      if (pos < TOPK) out_row[pos] = base + i;
      pos++;
    }
  }
}

// ---------------------------------------------------------------------------
// Scores: per (h,kk) stage k_c (204x64 fp32) in LDS; each thread owns one
// query, computes 204 raw scores (written coalesced as [hk][t][q]) and the
// online (max, sumexp) pair.
// ---------------------------------------------------------------------------
__global__ __launch_bounds__(256) void attn_scores(
    const float* __restrict__ q, const float* __restrict__ k,
    const int* __restrict__ topk, const int* __restrict__ clusters,
    float* __restrict__ scores, float* __restrict__ ml) {
  __shared__ float kc[TOPK][DH];
  __shared__ int idx[TOPK];
  int tid = threadIdx.x;
  int qb = blockIdx.x, kk = blockIdx.y, h = blockIdx.z;

  if (tid < TOPK) idx[tid] = topk[kk * TOPK + tid];
  __syncthreads();
  for (int e = tid; e < TOPK * DH; e += 256) {
    int r = e >> 6, c = e & 63;
    kc[r][c] = k[((long)h * N_TOK + idx[r]) * DH + c];
  }
  __syncthreads();

  int m_local = qb * 256 + tid;
  int tok = clusters[kk * 4 + (m_local >> 9)] * TPF + (m_local & 511);
  float qr[DH];
  const float4* qp4 = reinterpret_cast<const float4*>(q + ((long)h * N_TOK + tok) * DH);
#pragma unroll
  for (int d4 = 0; d4 < 16; d4++) {
    float4 v = qp4[d4];
    qr[d4 * 4 + 0] = v.x * 0.125f;
    qr[d4 * 4 + 1] = v.y * 0.125f;
    qr[d4 * 4 + 2] = v.z * 0.125f;
    qr[d4 * 4 + 3] = v.w * 0.125f;
  }

  float m = -1e30f, l = 0.f;
  float* srow = scores + (long)((h * 4 + kk) * TOPK) * MPC + m_local;
  for (int t = 0; t < TOPK; t++) {
    const float4* kr4 = reinterpret_cast<const float4*>(kc[t]);
    float s0 = 0.f, s1 = 0.f, s2 = 0.f, s3 = 0.f;
#pragma unroll
    for (int d4 = 0; d4 < 16; d4++) {
      float4 kv = kr4[d4];
      s0 += qr[d4 * 4 + 0] * kv.x;
      s1 += qr[d4 * 4 + 1] * kv.y;
      s2 += qr[d4 * 4 + 2] * kv.z;
      s3 += qr[d4 * 4 + 3] * kv.w;
    }
    float s = (s0 + s1) + (s2 + s3);
    srow[(long)t * MPC] = s;
    if (s > m) {
      l = l * __expf(m - s) + 1.f;
      m = s;
    } else {
      l += __expf(s - m);
    }
  }
  float2* mlp = reinterpret_cast<float2*>(ml);
  mlp[(h * 4 + kk) * MPC + m_local] = make_float2(m, l);
}

// ---------------------------------------------------------------------------
// Output: per (h,kk) stage v_c in LDS; each thread owns one query, reads its
// 204 scores (coalesced), accumulates o[64], writes x_attn[n][h*64+d].
// ---------------------------------------------------------------------------
__global__ __launch_bounds__(256) void attn_out(
    const float* __restrict__ v, const float* __restrict__ scores,
    const float* __restrict__ ml, const int* __restrict__ topk,
    const int* __restrict__ clusters, float* __restrict__ xattn) {
  __shared__ float vc[TOPK][DH];
  __shared__ int idx[TOPK];
  int tid = threadIdx.x;
  int qb = blockIdx.x, kk = blockIdx.y, h = blockIdx.z;

  if (tid < TOPK) idx[tid] = topk[kk * TOPK + tid];
  __syncthreads();
  for (int e = tid; e < TOPK * DH; e += 256) {
    int r = e >> 6, c = e & 63;
    vc[r][c] = v[((long)h * N_TOK + idx[r]) * DH + c];
  }
  __syncthreads();

  int m_local = qb * 256 + tid;
  const float2* mlp = reinterpret_cast<const float2*>(ml);
  float2 me = mlp[(h * 4 + kk) * MPC + m_local];

  float o[DH];
#pragma unroll
  for (int d = 0; d < DH; d++) o[d] = 0.f;

  const float* srow = scores + (long)((h * 4 + kk) * TOPK) * MPC + m_local;
  for (int t = 0; t < TOPK; t++) {
    float w = __expf(srow[(long)t * MPC] - me.x);
    const float4* vr4 = reinterpret_cast<const float4*>(vc[t]);
#pragma unroll
    for (int d4 = 0; d4 < 16; d4++) {
      float4 vv = vr4[d4];
      o[d4 * 4 + 0] += w * vv.x;
      o[d4 * 4 + 1] += w * vv.y;
      o[d4 * 4 + 2] += w * vv.z;
      o[d4 * 4 + 3] += w * vv.w;
    }
  }
  float inv = 1.f / me.y;
  int tok = clusters[kk * 4 + (m_local >> 9)] * TPF + (m_local & 511);
  float4* op = reinterpret_cast<float4*>(xattn + (long)tok * C_DIM + h * DH);
#pragma unroll
  for (int d4 = 0; d4 < 16; d4++) {
    op[d4] = make_float4(o[d4 * 4 + 0] * inv, o[d4 * 4 + 1] * inv,
                         o[d4 * 4 + 2] * inv, o[d4 * 4 + 3] * inv);
  }
}

// ---------------------------------------------------------------------------
extern "C" void kernel_launch(void* const* d_in, const int* in_sizes, int n_in,
                              void* d_out, int out_size, void* d_ws, size_t ws_size,
                              hipStream_t stream) {
  const float* x = (const float*)d_in[0];
  const float* w_qkv = (const float*)d_in[1];
  const float* b_qkv = (const float*)d_in[2];
  const float* w_proj = (const float*)d_in[3];
  const float* b_proj = (const float*)d_in[4];
  const int* keyframes = (const int*)d_in[5];
  const int* clusters = (const int*)d_in[6];
  float* out = (float*)d_out;
  float* ws = (float*)d_ws;

  float* q = ws + WS_Q;
  float* k = ws + WS_K;
  float* v = ws + WS_V;
  float* xattn = ws + WS_XATTN;
  float* qbar = ws + WS_QBAR;
  float* agg = ws + WS_AGG;
  float* ml = ws + WS_ML;
  float* scores = ws + WS_SCORES;
  int* topk = (int*)(ws + WS_TOPK);

  // 1. QKV GEMM (8192x1536x512) -> q/k/v [h][n][d]
  gemm_bt<1><<<dim3(1536 / 64, N_TOK / 64), dim3(16, 16), 0, stream>>>(
      x, w_qkv, b_qkv, ws, N_TOK, 1536, C_DIM);
  // 2. keyframe query means
  qbar_kernel<<<NH * KCLUST, DH, 0, stream>>>(q, keyframes, qbar);
  // 3. agg[kk][n]
  agg_kernel<<<N_TOK / 4, 256, 0, stream>>>(k, qbar, agg);
  // 4. top-204 per cluster row
  topk_kernel<<<KCLUST, 256, 0, stream>>>(agg, topk);
  // 5. attention scores + online softmax stats
  attn_scores<<<dim3(MPC / 256, KCLUST, NH), 256, 0, stream>>>(
      q, k, topk, clusters, scores, ml);
  // 6. attention output
  attn_out<<<dim3(MPC / 256, KCLUST, NH), 256, 0, stream>>>(
      v, scores, ml, topk, clusters, xattn);
  // 7. projection GEMM (8192x512x512) -> d_out
  gemm_bt<0><<<dim3(C_DIM / 64, N_TOK / 64), dim3(16, 16), 0, stream>>>(
      xattn, w_proj, b_proj, out, N_TOK, C_DIM, C_DIM);
}

// Round 2
// 398.244 us; speedup vs baseline: 1.4401x; 1.4401x over previous
//
#include <hip/hip_runtime.h>
#include <hip/hip_bf16.h>

#define N_TOK 8192
#define C_DIM 512
#define NH 8
#define DH 64
#define KCLUST 4
#define TPF 512
#define TOPK 204
#define MPC 2048

// ---- workspace layout (float offsets) ----
#define WS_Q      0            // q/k/v fp32 [3][h][n][d]
#define WS_K      4194304
#define WS_V      8388608
#define WS_XHI    12582912     // bf16 (as u16) x hi: 4194304 shorts = 2097152 floats
#define WS_XLO    14680064
#define WS_WQHI   16777216     // w_qkv bf16 hi: 786432 shorts = 393216 floats
#define WS_WQLO   17170432
#define WS_WPHI   17563648     // w_proj bf16: 262144 shorts = 131072 floats
#define WS_WPLO   17694720
#define WS_XAHI   17825792     // xattn bf16 hi: 4194304 shorts = 2097152 floats
#define WS_XALO   19922944
#define WS_XBARP  22020096     // 4*16*512
#define WS_XBAR   22052864     // 4*512
#define WS_QBAR   22054912     // 32*64
#define WS_GPART  22056960     // 4*8*512
#define WS_G      22073344     // 4*512
#define WS_AGG    22075392     // 4*8192
#define WS_TOPK   22108160     // ints 4*204

using frag16 = __attribute__((ext_vector_type(8))) short;
using f32x4  = __attribute__((ext_vector_type(4))) float;

#define GLL(g, l) __builtin_amdgcn_global_load_lds(                      \
    (const __attribute__((address_space(1))) void*)(const void*)(g),     \
    (__attribute__((address_space(3))) void*)(void*)(l), 16, 0, 0)

__device__ __forceinline__ unsigned short f2bf(float x) {
  unsigned u = __float_as_uint(x);
  return (unsigned short)((u + 0x7fffu + ((u >> 16) & 1u)) >> 16);
}
__device__ __forceinline__ float bf2f(unsigned short h) {
  return __uint_as_float(((unsigned)h) << 16);
}

// ---------------------------------------------------------------------------
// fp32 -> (bf16 hi, bf16 lo) split conversion; i indexes float4 groups.
// ---------------------------------------------------------------------------
__global__ __launch_bounds__(256) void cvt_split(const float* __restrict__ in,
                                                 unsigned short* __restrict__ hi,
                                                 unsigned short* __restrict__ lo,
                                                 int n4) {
  int i = blockIdx.x * 256 + threadIdx.x;
  if (i >= n4) return;
  float4 v = reinterpret_cast<const float4*>(in)[i];
  unsigned short h0 = f2bf(v.x), h1 = f2bf(v.y), h2 = f2bf(v.z), h3 = f2bf(v.w);
  reinterpret_cast<uint2*>(hi)[i] =
      make_uint2((unsigned)h0 | ((unsigned)h1 << 16), (unsigned)h2 | ((unsigned)h3 << 16));
  unsigned short l0 = f2bf(v.x - bf2f(h0)), l1 = f2bf(v.y - bf2f(h1));
  unsigned short l2 = f2bf(v.z - bf2f(h2)), l3 = f2bf(v.w - bf2f(h3));
  reinterpret_cast<uint2*>(lo)[i] =
      make_uint2((unsigned)l0 | ((unsigned)l1 << 16), (unsigned)l2 | ((unsigned)l3 << 16));
}

// ---------------------------------------------------------------------------
// Split-bf16 MFMA GEMM: out[m][j] = sum_c A[m][c]*B[j][c] + bias[j]
// A,B given as bf16 hi/lo pairs; 3 MFMA passes (hh + hl + lh) ~ fp32 accuracy.
// 128x128 tile, 4 waves, 16x16x32 MFMA, global_load_lds staging.
// LDS layout: panel p (k-octet) at short offset p*1024 + row*8.
// ---------------------------------------------------------------------------
template <int WRITE_QKV>
__global__ __launch_bounds__(256) void gemm_split(
    const unsigned short* __restrict__ Ahi, const unsigned short* __restrict__ Alo,
    const unsigned short* __restrict__ Bhi, const unsigned short* __restrict__ Blo,
    const float* __restrict__ bias, float* __restrict__ out, int Jdim, int Kdim) {
  __shared__ short As[2][4096];
  __shared__ short Bs[2][4096];
  const int tid = threadIdx.x;
  const int m0 = blockIdx.y * 128;
  const int j0 = blockIdx.x * 128;
  const int wave = tid >> 6, lane = tid & 63;
  const int wr = wave >> 1, wc = wave & 1;
  const int qd = lane >> 4, ln = lane & 15;

  f32x4 acc[4][4] = {};

  const int srow = tid & 127;
  const int sp = tid >> 7;

  for (int k0 = 0; k0 < Kdim; k0 += 32) {
#pragma unroll
    for (int i = 0; i < 2; i++) {
      int p = i * 2 + sp;
      size_t ga = (size_t)(m0 + srow) * Kdim + k0 + p * 8;
      size_t gb = (size_t)(j0 + srow) * Kdim + k0 + p * 8;
      int loff = p * 1024 + srow * 8;
      GLL(Ahi + ga, &As[0][loff]);
      GLL(Alo + ga, &As[1][loff]);
      GLL(Bhi + gb, &Bs[0][loff]);
      GLL(Blo + gb, &Bs[1][loff]);
    }
    __syncthreads();
    frag16 ah[4], al[4], bh[4], bl[4];
#pragma unroll
    for (int i = 0; i < 4; i++) {
      int ao = qd * 1024 + (wr * 64 + i * 16 + ln) * 8;
      int bo = qd * 1024 + (wc * 64 + i * 16 + ln) * 8;
      ah[i] = *reinterpret_cast<const frag16*>(&As[0][ao]);
      al[i] = *reinterpret_cast<const frag16*>(&As[1][ao]);
      bh[i] = *reinterpret_cast<const frag16*>(&Bs[0][bo]);
      bl[i] = *reinterpret_cast<const frag16*>(&Bs[1][bo]);
    }
#pragma unroll
    for (int i = 0; i < 4; i++)
#pragma unroll
      for (int j = 0; j < 4; j++) {
        acc[i][j] = __builtin_amdgcn_mfma_f32_16x16x32_bf16(ah[i], bh[j], acc[i][j], 0, 0, 0);
        acc[i][j] = __builtin_amdgcn_mfma_f32_16x16x32_bf16(ah[i], bl[j], acc[i][j], 0, 0, 0);
        acc[i][j] = __builtin_amdgcn_mfma_f32_16x16x32_bf16(al[i], bh[j], acc[i][j], 0, 0, 0);
      }
    __syncthreads();
  }

  // D[m][n]: n = j0 + wc*64 + j*16 + ln ; m = m0 + wr*64 + i*16 + qd*4 + r
#pragma unroll
  for (int i = 0; i < 4; i++)
#pragma unroll
    for (int j = 0; j < 4; j++)
#pragma unroll
      for (int r = 0; r < 4; r++) {
        int m = m0 + wr * 64 + i * 16 + qd * 4 + r;
        int jj = j0 + wc * 64 + j * 16 + ln;
        float val = acc[i][j][r] + bias[jj];
        if (WRITE_QKV) {
          int sel = jj >> 9, h = (jj >> 6) & 7, d = jj & 63;
          out[(size_t)sel * (NH * (size_t)N_TOK * DH) +
              ((size_t)h * N_TOK + m) * DH + d] = val;
        } else {
          out[(size_t)m * Jdim + jj] = val;
        }
      }
}

// ---------------------------------------------------------------------------
// xbar partials: block (kk,s) sums 32 tokens of keyframe kk over all 512 c.
// ---------------------------------------------------------------------------
__global__ __launch_bounds__(256) void xbar_part(const float* __restrict__ x,
                                                 const int* __restrict__ keyframes,
                                                 float* __restrict__ part) {
  int kk = blockIdx.x, s = blockIdx.y, tid = threadIdx.x;
  int base = keyframes[kk] * TPF + s * 32;
  float a0 = 0.f, a1 = 0.f;
  for (int t = 0; t < 32; t++) {
    a0 += x[(size_t)(base + t) * C_DIM + tid];
    a1 += x[(size_t)(base + t) * C_DIM + tid + 256];
  }
  part[(kk * 16 + s) * C_DIM + tid] = a0;
  part[(kk * 16 + s) * C_DIM + tid + 256] = a1;
}

__global__ void xbar_reduce(const float* __restrict__ part, float* __restrict__ xbar) {
  int kk = blockIdx.x, c = threadIdx.x;
  float a = 0.f;
  for (int s = 0; s < 16; s++) a += part[(kk * 16 + s) * C_DIM + c];
  xbar[kk * C_DIM + c] = a * (1.f / 512.f);
}

// ---------------------------------------------------------------------------
// qbar[h][kk][d] = W_q[h*64+d] . xbar[kk] + b_q  (fp32, exact mean via linearity)
// ---------------------------------------------------------------------------
__global__ __launch_bounds__(256) void qbar_k(const float* __restrict__ w_qkv,
                                              const float* __restrict__ b_qkv,
                                              const float* __restrict__ xbar,
                                              float* __restrict__ qbar) {
  __shared__ float xs[C_DIM];
  __shared__ float red[256];
  int blk = blockIdx.x, h = blk >> 2, kk = blk & 3, tid = threadIdx.x;
  for (int i = tid; i < C_DIM; i += 256) xs[i] = xbar[kk * C_DIM + i];
  __syncthreads();
  int d = tid & 63, pp = tid >> 6;
  const float* wrow = w_qkv + (size_t)(h * 64 + d) * C_DIM + pp * 128;
  float a = 0.f;
  for (int c = 0; c < 128; c++) a += wrow[c] * xs[pp * 128 + c];
  red[tid] = a;
  __syncthreads();
  if (pp == 0)
    qbar[(h * 4 + kk) * 64 + d] = red[d] + red[64 + d] + red[128 + d] + red[192 + d] +
                                  b_qkv[h * 64 + d];
}

// ---------------------------------------------------------------------------
// g partials: g[kk][c] = sum_hd qbar[h][kk][d] * W_k[hd][c]  (block = (kk,hh))
// ---------------------------------------------------------------------------
__global__ __launch_bounds__(256) void g_part(const float* __restrict__ w_qkv,
                                              const float* __restrict__ qbar,
                                              float* __restrict__ gp) {
  __shared__ float qs[64];
  int kk = blockIdx.x, hh = blockIdx.y, tid = threadIdx.x;
  if (tid < 64) qs[tid] = qbar[(hh * 4 + kk) * 64 + tid];
  __syncthreads();
  float a0 = 0.f, a1 = 0.f;
  for (int j = 0; j < 64; j++) {
    float qv = qs[j];
    const float* wr = w_qkv + (size_t)(C_DIM + hh * 64 + j) * C_DIM;
    a0 += qv * wr[tid];
    a1 += qv * wr[tid + 256];
  }
  gp[(kk * 8 + hh) * C_DIM + tid] = a0;
  gp[(kk * 8 + hh) * C_DIM + tid + 256] = a1;
}

__global__ void g_reduce(const float* __restrict__ gp, float* __restrict__ g) {
  int kk = blockIdx.x, c = threadIdx.x;
  float a = 0.f;
  for (int s = 0; s < 8; s++) a += gp[(kk * 8 + s) * C_DIM + c];
  g[kk * C_DIM + c] = a;
}

// ---------------------------------------------------------------------------
// agg[kk][n] = g[kk] . x[n]   (rank-equivalent to reference agg; fp32 exact-ish)
// ---------------------------------------------------------------------------
__global__ __launch_bounds__(256) void agg2_kernel(const float* __restrict__ x,
                                                   const float* __restrict__ g,
                                                   float* __restrict__ agg) {
  __shared__ float gs[KCLUST][C_DIM];
  int tid = threadIdx.x;
  for (int i = tid; i < KCLUST * C_DIM; i += 256) gs[i >> 9][i & 511] = g[i];
  __syncthreads();
  int wave = tid >> 6, lane = tid & 63;
  int n = blockIdx.x * 4 + wave;
  const float4* xp = reinterpret_cast<const float4*>(x + (size_t)n * C_DIM);
  float4 xa = xp[lane], xb = xp[lane + 64];
  float a[4];
#pragma unroll
  for (int kk = 0; kk < 4; kk++) {
    const float4* gpv = reinterpret_cast<const float4*>(&gs[kk][0]);
    float4 ga = gpv[lane], gb = gpv[lane + 64];
    a[kk] = xa.x * ga.x + xa.y * ga.y + xa.z * ga.z + xa.w * ga.w +
            xb.x * gb.x + xb.y * gb.y + xb.z * gb.z + xb.w * gb.w;
  }
#pragma unroll
  for (int off = 32; off >= 1; off >>= 1) {
    a[0] += __shfl_xor(a[0], off);
    a[1] += __shfl_xor(a[1], off);
    a[2] += __shfl_xor(a[2], off);
    a[3] += __shfl_xor(a[3], off);
  }
  if (lane == 0) {
    agg[0 * N_TOK + n] = a[0];
    agg[1 * N_TOK + n] = a[1];
    agg[2 * N_TOK + n] = a[2];
    agg[3 * N_TOK + n] = a[3];
  }
}

// ---------------------------------------------------------------------------
// Deterministic top-204 (radix select; ties -> lowest index). Unchanged (R1 pass).
// ---------------------------------------------------------------------------
__global__ __launch_bounds__(256) void topk_kernel(const float* __restrict__ agg,
                                                   int* __restrict__ topk) {
  __shared__ unsigned sk[N_TOK];
  __shared__ int cnt[256];
  __shared__ int scn[256];
  int kk = blockIdx.x, tid = threadIdx.x;
  const float* row = agg + (size_t)kk * N_TOK;

  for (int i = tid; i < N_TOK; i += 256) {
    unsigned u = __float_as_uint(row[i]);
    sk[i] = (u & 0x80000000u) ? ~u : (u | 0x80000000u);
  }
  __syncthreads();

  unsigned prefix = 0;
  int remaining = TOPK;
  for (int b = 31; b >= 0; b--) {
    unsigned cand = (prefix | (1u << b)) >> b;
    int c = 0;
    for (int i = tid; i < N_TOK; i += 256) c += ((sk[i] >> b) == cand) ? 1 : 0;
    cnt[tid] = c;
    __syncthreads();
    for (int s = 128; s > 0; s >>= 1) {
      if (tid < s) cnt[tid] += cnt[tid + s];
      __syncthreads();
    }
    int total = cnt[0];
    __syncthreads();
    if (total >= remaining) prefix |= (1u << b);
    else remaining -= total;
  }
  unsigned kth = prefix;

  int* out_row = topk + kk * TOPK;
  int base = tid * 32;

  int cA = 0;
  for (int i = 0; i < 32; i++) cA += (sk[base + i] > kth) ? 1 : 0;
  scn[tid] = cA;
  __syncthreads();
  for (int s = 1; s < 256; s <<= 1) {
    int add = (tid >= s) ? scn[tid - s] : 0;
    __syncthreads();
    scn[tid] += add;
    __syncthreads();
  }
  int exclA = scn[tid] - cA;
  int G = scn[255];
  __syncthreads();
  int p = exclA;
  for (int i = 0; i < 32; i++)
    if (sk[base + i] > kth) out_row[p++] = base + i;
  __syncthreads();

  int cB = 0;
  for (int i = 0; i < 32; i++) cB += (sk[base + i] == kth) ? 1 : 0;
  scn[tid] = cB;
  __syncthreads();
  for (int s = 1; s < 256; s <<= 1) {
    int add = (tid >= s) ? scn[tid - s] : 0;
    __syncthreads();
    scn[tid] += add;
    __syncthreads();
  }
  int exclB = scn[tid] - cB;
  int pos = G + exclB;
  for (int i = 0; i < 32; i++) {
    if (sk[base + i] == kth) {
      if (pos < TOPK) out_row[pos] = base + i;
      pos++;
    }
  }
}

// ---------------------------------------------------------------------------
// Fused flash attention. grid (MPC/64, KCLUST, NH), 256 thr.
// Wave: 16 queries x 4 t-lanes. k/v tiles of 64 staged in LDS (padded 68).
// No max-subtraction (scores bounded); output written as split bf16.
// ---------------------------------------------------------------------------
__global__ __launch_bounds__(256) void flash_attn(
    const float* __restrict__ q, const float* __restrict__ k,
    const float* __restrict__ v, const int* __restrict__ topk,
    const int* __restrict__ clusters, unsigned short* __restrict__ xahi,
    unsigned short* __restrict__ xalo) {
  __shared__ float kc[64][68];
  __shared__ float vc[64][68];
  __shared__ int idx[TOPK];
  int tid = threadIdx.x;
  int qb = blockIdx.x, kk = blockIdx.y, h = blockIdx.z;
  if (tid < TOPK) idx[tid] = topk[kk * TOPK + tid];

  int wave = tid >> 6, lane = tid & 63;
  int ts = lane >> 4, qs = lane & 15;
  int q_local = qb * 64 + wave * 16 + qs;
  int tok = clusters[kk * 4 + (q_local >> 9)] * TPF + (q_local & 511);

  float qr[64];
  const float4* qp = reinterpret_cast<const float4*>(q + ((size_t)h * N_TOK + tok) * DH);
#pragma unroll
  for (int i = 0; i < 16; i++) {
    float4 t = qp[i];
    qr[4 * i + 0] = t.x * 0.125f;
    qr[4 * i + 1] = t.y * 0.125f;
    qr[4 * i + 2] = t.z * 0.125f;
    qr[4 * i + 3] = t.w * 0.125f;
  }

  float o[64];
#pragma unroll
  for (int d = 0; d < 64; d++) o[d] = 0.f;
  float l = 0.f;

  __syncthreads();  // idx ready

  for (int t0 = 0; t0 < TOPK; t0 += 64) {
    int nt = TOPK - t0 < 64 ? TOPK - t0 : 64;
    // stage tile
#pragma unroll
    for (int i = 0; i < 4; i++) {
      int fid = tid + i * 256;
      int r = fid >> 4, c4 = fid & 15;
      if (t0 + r < TOPK) {
        size_t src = ((size_t)h * N_TOK + idx[t0 + r]) * DH;
        *reinterpret_cast<float4*>(&kc[r][c4 * 4]) =
            reinterpret_cast<const float4*>(k + src)[c4];
        *reinterpret_cast<float4*>(&vc[r][c4 * 4]) =
            reinterpret_cast<const float4*>(v + src)[c4];
      }
    }
    __syncthreads();
    int iters = nt >> 2;
    for (int i = 0; i < iters; i++) {
      int tl = ts + 4 * i;
      const float4* kr = reinterpret_cast<const float4*>(&kc[tl][0]);
      float s0 = 0.f, s1 = 0.f, s2 = 0.f, s3 = 0.f;
#pragma unroll
      for (int d4 = 0; d4 < 16; d4++) {
        float4 kv = kr[d4];
        s0 += qr[4 * d4 + 0] * kv.x;
        s1 += qr[4 * d4 + 1] * kv.y;
        s2 += qr[4 * d4 + 2] * kv.z;
        s3 += qr[4 * d4 + 3] * kv.w;
      }
      float w = __expf((s0 + s1) + (s2 + s3));
      l += w;
      const float4* vr = reinterpret_cast<const float4*>(&vc[tl][0]);
#pragma unroll
      for (int d4 = 0; d4 < 16; d4++) {
        float4 vv = vr[d4];
        o[4 * d4 + 0] += w * vv.x;
        o[4 * d4 + 1] += w * vv.y;
        o[4 * d4 + 2] += w * vv.z;
        o[4 * d4 + 3] += w * vv.w;
      }
    }
    __syncthreads();
  }

  // reduce partial sums across the 4 t-lanes (lane bits 4,5)
#pragma unroll
  for (int d = 0; d < 64; d++) {
    o[d] += __shfl_xor(o[d], 16);
    o[d] += __shfl_xor(o[d], 32);
  }
  l += __shfl_xor(l, 16);
  l += __shfl_xor(l, 32);
  float inv = 1.f / l;

  if (ts == 0) {
    unsigned* hd = reinterpret_cast<unsigned*>(xahi + (size_t)tok * C_DIM + h * DH);
    unsigned* ld = reinterpret_cast<unsigned*>(xalo + (size_t)tok * C_DIM + h * DH);
#pragma unroll
    for (int p = 0; p < 32; p++) {
      float a = o[2 * p] * inv, b = o[2 * p + 1] * inv;
      unsigned short ha = f2bf(a), hb = f2bf(b);
      hd[p] = (unsigned)ha | ((unsigned)hb << 16);
      unsigned short la = f2bf(a - bf2f(ha)), lb = f2bf(b - bf2f(hb));
      ld[p] = (unsigned)la | ((unsigned)lb << 16);
    }
  }
}

// ---------------------------------------------------------------------------
extern "C" void kernel_launch(void* const* d_in, const int* in_sizes, int n_in,
                              void* d_out, int out_size, void* d_ws, size_t ws_size,
                              hipStream_t stream) {
  const float* x = (const float*)d_in[0];
  const float* w_qkv = (const float*)d_in[1];
  const float* b_qkv = (const float*)d_in[2];
  const float* w_proj = (const float*)d_in[3];
  const float* b_proj = (const float*)d_in[4];
  const int* keyframes = (const int*)d_in[5];
  const int* clusters = (const int*)d_in[6];
  float* out = (float*)d_out;
  float* ws = (float*)d_ws;

  float* q = ws + WS_Q;
  float* k = ws + WS_K;
  float* v = ws + WS_V;
  unsigned short* xhi = (unsigned short*)(ws + WS_XHI);
  unsigned short* xlo = (unsigned short*)(ws + WS_XLO);
  unsigned short* wqhi = (unsigned short*)(ws + WS_WQHI);
  unsigned short* wqlo = (unsigned short*)(ws + WS_WQLO);
  unsigned short* wphi = (unsigned short*)(ws + WS_WPHI);
  unsigned short* wplo = (unsigned short*)(ws + WS_WPLO);
  unsigned short* xahi = (unsigned short*)(ws + WS_XAHI);
  unsigned short* xalo = (unsigned short*)(ws + WS_XALO);
  float* xbarp = ws + WS_XBARP;
  float* xbar = ws + WS_XBAR;
  float* qbar = ws + WS_QBAR;
  float* gpart = ws + WS_GPART;
  float* g = ws + WS_G;
  float* agg = ws + WS_AGG;
  int* topk = (int*)(ws + WS_TOPK);

  // bf16 split conversions
  cvt_split<<<4096, 256, 0, stream>>>(x, xhi, xlo, 1048576);
  cvt_split<<<768, 256, 0, stream>>>(w_qkv, wqhi, wqlo, 196608);
  cvt_split<<<256, 256, 0, stream>>>(w_proj, wphi, wplo, 65536);

  // QKV GEMM (MFMA, split) -> q/k/v fp32
  gemm_split<1><<<dim3(12, 64), 256, 0, stream>>>(xhi, xlo, wqhi, wqlo, b_qkv,
                                                  ws, 1536, C_DIM);

  // fp32 agg path (rank-exact): xbar -> qbar -> g -> agg -> topk
  xbar_part<<<dim3(4, 16), 256, 0, stream>>>(x, keyframes, xbarp);
  xbar_reduce<<<4, 512, 0, stream>>>(xbarp, xbar);
  qbar_k<<<32, 256, 0, stream>>>(w_qkv, b_qkv, xbar, qbar);
  g_part<<<dim3(4, 8), 256, 0, stream>>>(w_qkv, qbar, gpart);
  g_reduce<<<4, 512, 0, stream>>>(gpart, g);
  agg2_kernel<<<2048, 256, 0, stream>>>(x, g, agg);
  topk_kernel<<<4, 256, 0, stream>>>(agg, topk);

  // x_attn = 0 (uncovered rows must be exactly zero), then fused attention
  hipMemsetAsync(xahi, 0, (size_t)N_TOK * C_DIM * 2 * 2, stream);  // hi+lo contiguous
  flash_attn<<<dim3(MPC / 64, KCLUST, NH), 256, 0, stream>>>(q, k, v, topk,
                                                             clusters, xahi, xalo);

  // projection GEMM (MFMA, split) -> d_out
  gemm_split<0><<<dim3(4, 64), 256, 0, stream>>>(xahi, xalo, wphi, wplo, b_proj,
                                                 out, C_DIM, C_DIM);
}

// Round 3
// 307.521 us; speedup vs baseline: 1.8650x; 1.2950x over previous
//
#include <hip/hip_runtime.h>
#include <hip/hip_bf16.h>

#define N_TOK 8192
#define C_DIM 512
#define NH 8
#define DH 64
#define KCLUST 4
#define TPF 512
#define TOPK 204
#define MPC 2048

// ---- workspace layout (float offsets) ----
#define WS_XHI    0            // x bf16 hi: 4194304 shorts = 2097152 floats
#define WS_XLO    2097152
#define WS_WQHI   4194304      // w_qkv: 786432 shorts = 393216 floats
#define WS_WQLO   4587520
#define WS_WPHI   4980736      // w_proj: 262144 shorts = 131072 floats
#define WS_WPLO   5111808
#define WS_QKV    5242880      // q/k/v bf16 hi/lo: 6 arrays x 4194304 shorts
#define WS_XAHI   17825792     // xattn bf16 hi
#define WS_XALO   19922944
#define WS_XBARP  22020096     // 4*16*512
#define WS_XBAR   22052864
#define WS_QBAR   22054912
#define WS_GPART  22056960
#define WS_G      22073344
#define WS_AGG    22075392
#define WS_TOPK   22108160     // ints 4*204

// shorts-per-array inside the QKV block
#define QKV_ARR   4194304

using frag16 = __attribute__((ext_vector_type(8))) short;
using f32x4  = __attribute__((ext_vector_type(4))) float;

#define GLL(g, l) __builtin_amdgcn_global_load_lds(                      \
    (const __attribute__((address_space(1))) void*)(const void*)(g),     \
    (__attribute__((address_space(3))) void*)(void*)(l), 16, 0, 0)

__device__ __forceinline__ unsigned short f2bf(float x) {
  unsigned u = __float_as_uint(x);
  return (unsigned short)((u + 0x7fffu + ((u >> 16) & 1u)) >> 16);
}
__device__ __forceinline__ float bf2f(unsigned short h) {
  return __uint_as_float(((unsigned)h) << 16);
}

// ---------------------------------------------------------------------------
// fp32 -> (bf16 hi, bf16 lo) split conversion; i indexes float4 groups.
// ---------------------------------------------------------------------------
__global__ __launch_bounds__(256) void cvt_split(const float* __restrict__ in,
                                                 unsigned short* __restrict__ hi,
                                                 unsigned short* __restrict__ lo,
                                                 int n4) {
  int i = blockIdx.x * 256 + threadIdx.x;
  if (i >= n4) return;
  float4 v = reinterpret_cast<const float4*>(in)[i];
  unsigned short h0 = f2bf(v.x), h1 = f2bf(v.y), h2 = f2bf(v.z), h3 = f2bf(v.w);
  reinterpret_cast<uint2*>(hi)[i] =
      make_uint2((unsigned)h0 | ((unsigned)h1 << 16), (unsigned)h2 | ((unsigned)h3 << 16));
  unsigned short l0 = f2bf(v.x - bf2f(h0)), l1 = f2bf(v.y - bf2f(h1));
  unsigned short l2 = f2bf(v.z - bf2f(h2)), l3 = f2bf(v.w - bf2f(h3));
  reinterpret_cast<uint2*>(lo)[i] =
      make_uint2((unsigned)l0 | ((unsigned)l1 << 16), (unsigned)l2 | ((unsigned)l3 << 16));
}

// ---------------------------------------------------------------------------
// Split-bf16 MFMA GEMM (3 passes ~ fp32). 128x128 tile, 16x16x32 MFMA.
// MODE 0: out = float [M][Jdim] (+bias).  MODE 1: out = qkv bf16 hi/lo block,
// q (sel 0) pre-scaled by 0.125 (exact).
// ---------------------------------------------------------------------------
template <int MODE>
__global__ __launch_bounds__(256) void gemm_split(
    const unsigned short* __restrict__ Ahi, const unsigned short* __restrict__ Alo,
    const unsigned short* __restrict__ Bhi, const unsigned short* __restrict__ Blo,
    const float* __restrict__ bias, void* __restrict__ out_p, int Jdim, int Kdim) {
  __shared__ short As[2][4096];
  __shared__ short Bs[2][4096];
  const int tid = threadIdx.x;
  const int m0 = blockIdx.y * 128;
  const int j0 = blockIdx.x * 128;
  const int wave = tid >> 6, lane = tid & 63;
  const int wr = wave >> 1, wc = wave & 1;
  const int qd = lane >> 4, ln = lane & 15;

  f32x4 acc[4][4] = {};

  const int srow = tid & 127;
  const int sp = tid >> 7;

  for (int k0 = 0; k0 < Kdim; k0 += 32) {
#pragma unroll
    for (int i = 0; i < 2; i++) {
      int p = i * 2 + sp;
      size_t ga = (size_t)(m0 + srow) * Kdim + k0 + p * 8;
      size_t gb = (size_t)(j0 + srow) * Kdim + k0 + p * 8;
      int loff = p * 1024 + srow * 8;
      GLL(Ahi + ga, &As[0][loff]);
      GLL(Alo + ga, &As[1][loff]);
      GLL(Bhi + gb, &Bs[0][loff]);
      GLL(Blo + gb, &Bs[1][loff]);
    }
    __syncthreads();
    frag16 ah[4], al[4], bh[4], bl[4];
#pragma unroll
    for (int i = 0; i < 4; i++) {
      int ao = qd * 1024 + (wr * 64 + i * 16 + ln) * 8;
      int bo = qd * 1024 + (wc * 64 + i * 16 + ln) * 8;
      ah[i] = *reinterpret_cast<const frag16*>(&As[0][ao]);
      al[i] = *reinterpret_cast<const frag16*>(&As[1][ao]);
      bh[i] = *reinterpret_cast<const frag16*>(&Bs[0][bo]);
      bl[i] = *reinterpret_cast<const frag16*>(&Bs[1][bo]);
    }
#pragma unroll
    for (int i = 0; i < 4; i++)
#pragma unroll
      for (int j = 0; j < 4; j++) {
        acc[i][j] = __builtin_amdgcn_mfma_f32_16x16x32_bf16(ah[i], bh[j], acc[i][j], 0, 0, 0);
        acc[i][j] = __builtin_amdgcn_mfma_f32_16x16x32_bf16(ah[i], bl[j], acc[i][j], 0, 0, 0);
        acc[i][j] = __builtin_amdgcn_mfma_f32_16x16x32_bf16(al[i], bh[j], acc[i][j], 0, 0, 0);
      }
    __syncthreads();
  }

#pragma unroll
  for (int i = 0; i < 4; i++)
#pragma unroll
    for (int j = 0; j < 4; j++)
#pragma unroll
      for (int r = 0; r < 4; r++) {
        int m = m0 + wr * 64 + i * 16 + qd * 4 + r;
        int jj = j0 + wc * 64 + j * 16 + ln;
        float val = acc[i][j][r] + bias[jj];
        if (MODE == 1) {
          int sel = jj >> 9, hh = (jj >> 6) & 7, d = jj & 63;
          if (sel == 0) val *= 0.125f;  // fold attention scale into q (exact)
          size_t off = ((size_t)hh * N_TOK + m) * DH + d;
          unsigned short* hi = (unsigned short*)out_p + (size_t)sel * (2 * QKV_ARR) + off;
          unsigned short hv = f2bf(val);
          hi[0] = hv;
          hi[QKV_ARR] = f2bf(val - bf2f(hv));
        } else {
          ((float*)out_p)[(size_t)m * Jdim + jj] = val;
        }
      }
}

// ---------------------------------------------------------------------------
// fp32 agg path (rank-exact): xbar -> qbar -> g -> agg
// ---------------------------------------------------------------------------
__global__ __launch_bounds__(256) void xbar_part(const float* __restrict__ x,
                                                 const int* __restrict__ keyframes,
                                                 float* __restrict__ part) {
  int kk = blockIdx.x, s = blockIdx.y, tid = threadIdx.x;
  int base = keyframes[kk] * TPF + s * 32;
  float a0 = 0.f, a1 = 0.f;
  for (int t = 0; t < 32; t++) {
    a0 += x[(size_t)(base + t) * C_DIM + tid];
    a1 += x[(size_t)(base + t) * C_DIM + tid + 256];
  }
  part[(kk * 16 + s) * C_DIM + tid] = a0;
  part[(kk * 16 + s) * C_DIM + tid + 256] = a1;
}

__global__ void xbar_reduce(const float* __restrict__ part, float* __restrict__ xbar) {
  int kk = blockIdx.x, c = threadIdx.x;
  float a = 0.f;
  for (int s = 0; s < 16; s++) a += part[(kk * 16 + s) * C_DIM + c];
  xbar[kk * C_DIM + c] = a * (1.f / 512.f);
}

__global__ __launch_bounds__(256) void qbar_k(const float* __restrict__ w_qkv,
                                              const float* __restrict__ b_qkv,
                                              const float* __restrict__ xbar,
                                              float* __restrict__ qbar) {
  __shared__ float xs[C_DIM];
  __shared__ float red[256];
  int blk = blockIdx.x, h = blk >> 2, kk = blk & 3, tid = threadIdx.x;
  for (int i = tid; i < C_DIM; i += 256) xs[i] = xbar[kk * C_DIM + i];
  __syncthreads();
  int d = tid & 63, pp = tid >> 6;
  const float* wrow = w_qkv + (size_t)(h * 64 + d) * C_DIM + pp * 128;
  float a = 0.f;
  for (int c = 0; c < 128; c++) a += wrow[c] * xs[pp * 128 + c];
  red[tid] = a;
  __syncthreads();
  if (pp == 0)
    qbar[(h * 4 + kk) * 64 + d] = red[d] + red[64 + d] + red[128 + d] + red[192 + d] +
                                  b_qkv[h * 64 + d];
}

__global__ __launch_bounds__(256) void g_part(const float* __restrict__ w_qkv,
                                              const float* __restrict__ qbar,
                                              float* __restrict__ gp) {
  __shared__ float qs[64];
  int kk = blockIdx.x, hh = blockIdx.y, tid = threadIdx.x;
  if (tid < 64) qs[tid] = qbar[(hh * 4 + kk) * 64 + tid];
  __syncthreads();
  float a0 = 0.f, a1 = 0.f;
  for (int j = 0; j < 64; j++) {
    float qv = qs[j];
    const float* wr = w_qkv + (size_t)(C_DIM + hh * 64 + j) * C_DIM;
    a0 += qv * wr[tid];
    a1 += qv * wr[tid + 256];
  }
  gp[(kk * 8 + hh) * C_DIM + tid] = a0;
  gp[(kk * 8 + hh) * C_DIM + tid + 256] = a1;
}

__global__ void g_reduce(const float* __restrict__ gp, float* __restrict__ g) {
  int kk = blockIdx.x, c = threadIdx.x;
  float a = 0.f;
  for (int s = 0; s < 8; s++) a += gp[(kk * 8 + s) * C_DIM + c];
  g[kk * C_DIM + c] = a;
}

__global__ __launch_bounds__(256) void agg2_kernel(const float* __restrict__ x,
                                                   const float* __restrict__ g,
                                                   float* __restrict__ agg) {
  __shared__ float gs[KCLUST][C_DIM];
  int tid = threadIdx.x;
  for (int i = tid; i < KCLUST * C_DIM; i += 256) gs[i >> 9][i & 511] = g[i];
  __syncthreads();
  int wave = tid >> 6, lane = tid & 63;
  int n = blockIdx.x * 4 + wave;
  const float4* xp = reinterpret_cast<const float4*>(x + (size_t)n * C_DIM);
  float4 xa = xp[lane], xb = xp[lane + 64];
  float a[4];
#pragma unroll
  for (int kk = 0; kk < 4; kk++) {
    const float4* gpv = reinterpret_cast<const float4*>(&gs[kk][0]);
    float4 ga = gpv[lane], gb = gpv[lane + 64];
    a[kk] = xa.x * ga.x + xa.y * ga.y + xa.z * ga.z + xa.w * ga.w +
            xb.x * gb.x + xb.y * gb.y + xb.z * gb.z + xb.w * gb.w;
  }
#pragma unroll
  for (int off = 32; off >= 1; off >>= 1) {
    a[0] += __shfl_xor(a[0], off);
    a[1] += __shfl_xor(a[1], off);
    a[2] += __shfl_xor(a[2], off);
    a[3] += __shfl_xor(a[3], off);
  }
  if (lane == 0) {
    agg[0 * N_TOK + n] = a[0];
    agg[1 * N_TOK + n] = a[1];
    agg[2 * N_TOK + n] = a[2];
    agg[3 * N_TOK + n] = a[3];
  }
}

// ---------------------------------------------------------------------------
// Deterministic top-204 (radix select; ties -> lowest index).
// ---------------------------------------------------------------------------
__global__ __launch_bounds__(256) void topk_kernel(const float* __restrict__ agg,
                                                   int* __restrict__ topk) {
  __shared__ unsigned sk[N_TOK];
  __shared__ int cnt[256];
  __shared__ int scn[256];
  int kk = blockIdx.x, tid = threadIdx.x;
  const float* row = agg + (size_t)kk * N_TOK;

  for (int i = tid; i < N_TOK; i += 256) {
    unsigned u = __float_as_uint(row[i]);
    sk[i] = (u & 0x80000000u) ? ~u : (u | 0x80000000u);
  }
  __syncthreads();

  unsigned prefix = 0;
  int remaining = TOPK;
  for (int b = 31; b >= 0; b--) {
    unsigned cand = (prefix | (1u << b)) >> b;
    int c = 0;
    for (int i = tid; i < N_TOK; i += 256) c += ((sk[i] >> b) == cand) ? 1 : 0;
    cnt[tid] = c;
    __syncthreads();
    for (int s = 128; s > 0; s >>= 1) {
      if (tid < s) cnt[tid] += cnt[tid + s];
      __syncthreads();
    }
    int total = cnt[0];
    __syncthreads();
    if (total >= remaining) prefix |= (1u << b);
    else remaining -= total;
  }
  unsigned kth = prefix;

  int* out_row = topk + kk * TOPK;
  int base = tid * 32;

  int cA = 0;
  for (int i = 0; i < 32; i++) cA += (sk[base + i] > kth) ? 1 : 0;
  scn[tid] = cA;
  __syncthreads();
  for (int s = 1; s < 256; s <<= 1) {
    int add = (tid >= s) ? scn[tid - s] : 0;
    __syncthreads();
    scn[tid] += add;
    __syncthreads();
  }
  int exclA = scn[tid] - cA;
  int G = scn[255];
  __syncthreads();
  int p = exclA;
  for (int i = 0; i < 32; i++)
    if (sk[base + i] > kth) out_row[p++] = base + i;
  __syncthreads();

  int cB = 0;
  for (int i = 0; i < 32; i++) cB += (sk[base + i] == kth) ? 1 : 0;
  scn[tid] = cB;
  __syncthreads();
  for (int s = 1; s < 256; s <<= 1) {
    int add = (tid >= s) ? scn[tid - s] : 0;
    __syncthreads();
    scn[tid] += add;
    __syncthreads();
  }
  int exclB = scn[tid] - cB;
  int pos = G + exclB;
  for (int i = 0; i < 32; i++) {
    if (sk[base + i] == kth) {
      if (pos < TOPK) out_row[pos] = base + i;
      pos++;
    }
  }
}

// ---------------------------------------------------------------------------
// MFMA flash attention. grid (MPC/64, KCLUST, NH), 256 thr (4 waves).
// Wave owns 16 q rows. K-tiles of 64 keys; split-bf16 (3 MFMA passes) for
// QK^T and PV. P round-trips LDS (C-layout -> A-layout), stride 72 shorts
// (16B-aligned, 2-way-conflict-free). No max subtraction (scores bounded).
// ---------------------------------------------------------------------------
__global__ __launch_bounds__(256) void flash_mfma(
    const unsigned short* __restrict__ qkv, const int* __restrict__ topk,
    const int* __restrict__ clusters, unsigned short* __restrict__ xahi,
    unsigned short* __restrict__ xalo) {
  __shared__ short Ks[2][64 * 72];
  __shared__ short Vs[2][64 * 72];
  __shared__ short Ps[2][64 * 72];
  __shared__ int idx[TOPK];
  const int tid = threadIdx.x;
  const int qb = blockIdx.x, kk = blockIdx.y, h = blockIdx.z;
  const int wave = tid >> 6, lane = tid & 63;
  const int ln = lane & 15, qd = lane >> 4;

  for (int i = tid; i < TOPK; i += 256) idx[i] = topk[kk * TOPK + i];

  const unsigned short* qhi = qkv;
  const unsigned short* qlo = qkv + QKV_ARR;
  const unsigned short* khi = qkv + 2 * QKV_ARR;
  const unsigned short* klo = qkv + 3 * QKV_ARR;
  const unsigned short* vhi = qkv + 4 * QKV_ARR;
  const unsigned short* vlo = qkv + 5 * QKV_ARR;

  const int q_local0 = qb * 64;
  const int frame = clusters[kk * 4 + (q_local0 >> 9)];
  const int tokbase = frame * TPF + (q_local0 & 511);

  // Q A-fragments (reused across all K tiles): row m = ln
  frag16 qa_h[2], qa_l[2];
  {
    const int tok_m = tokbase + wave * 16 + ln;
    const unsigned short* qr_h = qhi + ((size_t)h * N_TOK + tok_m) * DH;
    const unsigned short* qr_l = qlo + ((size_t)h * N_TOK + tok_m) * DH;
#pragma unroll
    for (int s = 0; s < 2; s++) {
      int koff = s * 32 + qd * 8;
      qa_h[s] = *reinterpret_cast<const frag16*>(qr_h + koff);
      qa_l[s] = *reinterpret_cast<const frag16*>(qr_l + koff);
    }
  }

  f32x4 acc_o[4] = {};
  float lsum[4] = {0.f, 0.f, 0.f, 0.f};

  __syncthreads();  // idx visible

  for (int t0 = 0; t0 < TOPK; t0 += 64) {
    // stage K tile (rows = keys, cols = d), clamp gather rows
#pragma unroll
    for (int i = 0; i < 4; i++) {
      int u = tid + i * 256;
      int arr = u >> 9, rem = u & 511;
      int r = rem >> 3, oct = rem & 7;
      int t = t0 + r;
      if (t > TOPK - 1) t = TOPK - 1;
      const unsigned short* src =
          (arr ? klo : khi) + ((size_t)h * N_TOK + idx[t]) * DH + oct * 8;
      *reinterpret_cast<frag16*>(&Ks[arr][r * 72 + oct * 8]) =
          *reinterpret_cast<const frag16*>(src);
    }
    // stage V transposed (rows = d, cols = keys)
#pragma unroll
    for (int i = 0; i < 8; i++) {
      int u = tid + i * 256;
      int arr = u >> 10, rem = u & 1023;
      int t = rem >> 4, d4 = (rem & 15) * 4;
      int tt = t0 + t;
      if (tt > TOPK - 1) tt = TOPK - 1;
      const unsigned short* src =
          (arr ? vlo : vhi) + ((size_t)h * N_TOK + idx[tt]) * DH + d4;
      uint2 w2 = *reinterpret_cast<const uint2*>(src);
      Vs[arr][(d4 + 0) * 72 + t] = (short)(w2.x & 0xffff);
      Vs[arr][(d4 + 1) * 72 + t] = (short)(w2.x >> 16);
      Vs[arr][(d4 + 2) * 72 + t] = (short)(w2.y & 0xffff);
      Vs[arr][(d4 + 3) * 72 + t] = (short)(w2.y >> 16);
    }
    __syncthreads();

    // S = Q K^T : 4 col-tiles x 2 k-steps x 3 passes
    f32x4 sacc[4] = {};
#pragma unroll
    for (int c = 0; c < 4; c++) {
#pragma unroll
      for (int s = 0; s < 2; s++) {
        int bo = (c * 16 + ln) * 72 + s * 32 + qd * 8;
        frag16 bh = *reinterpret_cast<const frag16*>(&Ks[0][bo]);
        frag16 bl = *reinterpret_cast<const frag16*>(&Ks[1][bo]);
        sacc[c] = __builtin_amdgcn_mfma_f32_16x16x32_bf16(qa_h[s], bh, sacc[c], 0, 0, 0);
        sacc[c] = __builtin_amdgcn_mfma_f32_16x16x32_bf16(qa_h[s], bl, sacc[c], 0, 0, 0);
        sacc[c] = __builtin_amdgcn_mfma_f32_16x16x32_bf16(qa_l[s], bh, sacc[c], 0, 0, 0);
      }
    }

    // P = exp(S) masked; write to LDS in [q][t] (A-layout source), sum l
#pragma unroll
    for (int c = 0; c < 4; c++) {
#pragma unroll
      for (int r = 0; r < 4; r++) {
        int tg = t0 + c * 16 + ln;
        float p = (tg < TOPK) ? __expf(sacc[c][r]) : 0.f;
        lsum[r] += p;
        int prow = wave * 16 + qd * 4 + r;
        unsigned short ph = f2bf(p);
        Ps[0][prow * 72 + c * 16 + ln] = (short)ph;
        Ps[1][prow * 72 + c * 16 + ln] = (short)f2bf(p - bf2f(ph));
      }
    }
    // own-wave LDS RAW: compiler inserts lgkmcnt wait (no barrier needed)

    // O += P V : A = P rows (own wave's 16 q), B = V^T rows (d)
#pragma unroll
    for (int s = 0; s < 2; s++) {
      int ao = (wave * 16 + ln) * 72 + s * 32 + qd * 8;
      frag16 pah = *reinterpret_cast<const frag16*>(&Ps[0][ao]);
      frag16 pal = *reinterpret_cast<const frag16*>(&Ps[1][ao]);
#pragma unroll
      for (int dt = 0; dt < 4; dt++) {
        int bo = (dt * 16 + ln) * 72 + s * 32 + qd * 8;
        frag16 vbh = *reinterpret_cast<const frag16*>(&Vs[0][bo]);
        frag16 vbl = *reinterpret_cast<const frag16*>(&Vs[1][bo]);
        acc_o[dt] = __builtin_amdgcn_mfma_f32_16x16x32_bf16(pah, vbh, acc_o[dt], 0, 0, 0);
        acc_o[dt] = __builtin_amdgcn_mfma_f32_16x16x32_bf16(pah, vbl, acc_o[dt], 0, 0, 0);
        acc_o[dt] = __builtin_amdgcn_mfma_f32_16x16x32_bf16(pal, vbh, acc_o[dt], 0, 0, 0);
      }
    }
    __syncthreads();  // protect Ks/Vs before next staging
  }

  // reduce l across the 16 col-lanes sharing each row group
#pragma unroll
  for (int r = 0; r < 4; r++) {
    float l = lsum[r];
    l += __shfl_xor(l, 1);
    l += __shfl_xor(l, 2);
    l += __shfl_xor(l, 4);
    l += __shfl_xor(l, 8);
    lsum[r] = 1.f / l;
  }

  // write O (C-layout: col=ln within d-tile, row=qd*4+r) as bf16 hi/lo
#pragma unroll
  for (int dt = 0; dt < 4; dt++)
#pragma unroll
    for (int r = 0; r < 4; r++) {
      float val = acc_o[dt][r] * lsum[r];
      int row = wave * 16 + qd * 4 + r;
      int tok = tokbase + row;
      size_t addr = (size_t)tok * C_DIM + h * DH + dt * 16 + ln;
      unsigned short hv = f2bf(val);
      xahi[addr] = hv;
      xalo[addr] = f2bf(val - bf2f(hv));
    }
}

// ---------------------------------------------------------------------------
extern "C" void kernel_launch(void* const* d_in, const int* in_sizes, int n_in,
                              void* d_out, int out_size, void* d_ws, size_t ws_size,
                              hipStream_t stream) {
  const float* x = (const float*)d_in[0];
  const float* w_qkv = (const float*)d_in[1];
  const float* b_qkv = (const float*)d_in[2];
  const float* w_proj = (const float*)d_in[3];
  const float* b_proj = (const float*)d_in[4];
  const int* keyframes = (const int*)d_in[5];
  const int* clusters = (const int*)d_in[6];
  float* out = (float*)d_out;
  float* ws = (float*)d_ws;

  unsigned short* xhi = (unsigned short*)(ws + WS_XHI);
  unsigned short* xlo = (unsigned short*)(ws + WS_XLO);
  unsigned short* wqhi = (unsigned short*)(ws + WS_WQHI);
  unsigned short* wqlo = (unsigned short*)(ws + WS_WQLO);
  unsigned short* wphi = (unsigned short*)(ws + WS_WPHI);
  unsigned short* wplo = (unsigned short*)(ws + WS_WPLO);
  unsigned short* qkv = (unsigned short*)(ws + WS_QKV);
  unsigned short* xahi = (unsigned short*)(ws + WS_XAHI);
  unsigned short* xalo = (unsigned short*)(ws + WS_XALO);
  float* xbarp = ws + WS_XBARP;
  float* xbar = ws + WS_XBAR;
  float* qbar = ws + WS_QBAR;
  float* gpart = ws + WS_GPART;
  float* g = ws + WS_G;
  float* agg = ws + WS_AGG;
  int* topk = (int*)(ws + WS_TOPK);

  // bf16 split conversions
  cvt_split<<<4096, 256, 0, stream>>>(x, xhi, xlo, 1048576);
  cvt_split<<<768, 256, 0, stream>>>(w_qkv, wqhi, wqlo, 196608);
  cvt_split<<<256, 256, 0, stream>>>(w_proj, wphi, wplo, 65536);

  // QKV GEMM -> q/k/v bf16 hi/lo (q pre-scaled by 0.125)
  gemm_split<1><<<dim3(12, 64), 256, 0, stream>>>(xhi, xlo, wqhi, wqlo, b_qkv,
                                                  qkv, 1536, C_DIM);

  // fp32 agg path (rank-exact): xbar -> qbar -> g -> agg -> topk
  xbar_part<<<dim3(4, 16), 256, 0, stream>>>(x, keyframes, xbarp);
  xbar_reduce<<<4, 512, 0, stream>>>(xbarp, xbar);
  qbar_k<<<32, 256, 0, stream>>>(w_qkv, b_qkv, xbar, qbar);
  g_part<<<dim3(4, 8), 256, 0, stream>>>(w_qkv, qbar, gpart);
  g_reduce<<<4, 512, 0, stream>>>(gpart, g);
  agg2_kernel<<<2048, 256, 0, stream>>>(x, g, agg);
  topk_kernel<<<4, 256, 0, stream>>>(agg, topk);

  // fused MFMA attention (clusters cover all tokens -> no memset needed)
  flash_mfma<<<dim3(MPC / 64, KCLUST, NH), 256, 0, stream>>>(qkv, topk,
                                                             clusters, xahi, xalo);

  // projection GEMM -> d_out
  gemm_split<0><<<dim3(4, 64), 256, 0, stream>>>(xahi, xalo, wphi, wplo, b_proj,
                                                 out, C_DIM, C_DIM);
}

// Round 4
// 252.476 us; speedup vs baseline: 2.2716x; 1.2180x over previous
//
#include <hip/hip_runtime.h>
#include <hip/hip_bf16.h>

#define N_TOK 8192
#define C_DIM 512
#define NH 8
#define DH 64
#define KCLUST 4
#define TPF 512
#define TOPK 204
#define MPC 2048

// ---- workspace layout (float offsets) ----
#define WS_XHI    0            // x hi: 4194304 shorts = 2097152 floats
#define WS_XLO    2097152
#define WS_WQH    4194304      // w_qkv hi: 786432 shorts = 393216 floats
#define WS_WPH    4587520      // w_proj hi: 262144 shorts = 131072 floats
#define WS_QHI    4718592      // q hi: 4194304 shorts = 2097152 floats
#define WS_QLO    6815744
#define WS_KHI    8912896
#define WS_VHI    11010048
#define WS_XAHI   13107200     // xattn hi
#define WS_XBARP  15204352     // 4*16*512
#define WS_XBAR   15237120
#define WS_QBAR   15239168
#define WS_GPART  15241216
#define WS_G      15257600
#define WS_AGG    15259648
#define WS_TOPK   15292416     // ints 4*204

using frag16 = __attribute__((ext_vector_type(8))) short;
using f32x4  = __attribute__((ext_vector_type(4))) float;

#define GLL(g, l) __builtin_amdgcn_global_load_lds(                      \
    (const __attribute__((address_space(1))) void*)(const void*)(g),     \
    (__attribute__((address_space(3))) void*)(void*)(l), 16, 0, 0)

__device__ __forceinline__ unsigned short f2bf(float x) {
  unsigned u = __float_as_uint(x);
  return (unsigned short)((u + 0x7fffu + ((u >> 16) & 1u)) >> 16);
}
__device__ __forceinline__ float bf2f(unsigned short h) {
  return __uint_as_float(((unsigned)h) << 16);
}

// ---------------------------------------------------------------------------
// fp32 -> bf16 hi (+ optional lo) conversion; i indexes float4 groups.
// ---------------------------------------------------------------------------
__global__ __launch_bounds__(256) void cvt_split(const float* __restrict__ in,
                                                 unsigned short* __restrict__ hi,
                                                 unsigned short* __restrict__ lo,
                                                 int n4) {
  int i = blockIdx.x * 256 + threadIdx.x;
  if (i >= n4) return;
  float4 v = reinterpret_cast<const float4*>(in)[i];
  unsigned short h0 = f2bf(v.x), h1 = f2bf(v.y), h2 = f2bf(v.z), h3 = f2bf(v.w);
  reinterpret_cast<uint2*>(hi)[i] =
      make_uint2((unsigned)h0 | ((unsigned)h1 << 16), (unsigned)h2 | ((unsigned)h3 << 16));
  unsigned short l0 = f2bf(v.x - bf2f(h0)), l1 = f2bf(v.y - bf2f(h1));
  unsigned short l2 = f2bf(v.z - bf2f(h2)), l3 = f2bf(v.w - bf2f(h3));
  reinterpret_cast<uint2*>(lo)[i] =
      make_uint2((unsigned)l0 | ((unsigned)l1 << 16), (unsigned)l2 | ((unsigned)l3 << 16));
}

__global__ __launch_bounds__(256) void cvt_hi(const float* __restrict__ in,
                                              unsigned short* __restrict__ hi,
                                              int n4) {
  int i = blockIdx.x * 256 + threadIdx.x;
  if (i >= n4) return;
  float4 v = reinterpret_cast<const float4*>(in)[i];
  unsigned short h0 = f2bf(v.x), h1 = f2bf(v.y), h2 = f2bf(v.z), h3 = f2bf(v.w);
  reinterpret_cast<uint2*>(hi)[i] =
      make_uint2((unsigned)h0 | ((unsigned)h1 << 16), (unsigned)h2 | ((unsigned)h3 << 16));
}

// ---------------------------------------------------------------------------
// QKV GEMM: 64x128 tile (m x j), 2-pass split (Ah*Bh + Al*Bh), grid (12,128)
// = 1536 blocks = 6/CU. Epilogue: q (hi/lo, pre-scaled 0.125), k hi, v hi.
// ---------------------------------------------------------------------------
__global__ __launch_bounds__(256) void gemm_qkv(
    const unsigned short* __restrict__ Ahi, const unsigned short* __restrict__ Alo,
    const unsigned short* __restrict__ Bhi, const float* __restrict__ bias,
    unsigned short* __restrict__ qhi, unsigned short* __restrict__ qlo,
    unsigned short* __restrict__ khi, unsigned short* __restrict__ vhi) {
  __shared__ short Ah[2048];   // 64 rows x 32 k (panel-major)
  __shared__ short Al[2048];
  __shared__ short Bh[4096];   // 128 rows x 32 k
  const int tid = threadIdx.x;
  const int j0 = blockIdx.x * 128;
  const int m0 = blockIdx.y * 64;
  const int wave = tid >> 6, lane = tid & 63;
  const int rh = wave >> 1, ch = wave & 1;
  const int qd = lane >> 4, ln = lane & 15;

  f32x4 acc[2][4] = {};

  for (int k0 = 0; k0 < C_DIM; k0 += 32) {
    // 16 staging wave-slots: 0-3 Ah panels, 4-7 Al panels, 8-15 Bh
#pragma unroll
    for (int s = 0; s < 4; s++) {
      int t = wave * 4 + s;
      if (t < 4) {
        GLL(Ahi + (size_t)(m0 + lane) * C_DIM + k0 + t * 8, &Ah[t * 512 + lane * 8]);
      } else if (t < 8) {
        int p = t - 4;
        GLL(Alo + (size_t)(m0 + lane) * C_DIM + k0 + p * 8, &Al[p * 512 + lane * 8]);
      } else {
        int p = (t - 8) >> 1, hf = (t - 8) & 1;
        GLL(Bhi + (size_t)(j0 + hf * 64 + lane) * C_DIM + k0 + p * 8,
            &Bh[p * 1024 + (hf * 64 + lane) * 8]);
      }
    }
    __syncthreads();
    frag16 a_h[2], a_l[2], b_h[4];
#pragma unroll
    for (int i = 0; i < 2; i++) {
      int row = rh * 32 + i * 16 + ln;
      a_h[i] = *reinterpret_cast<const frag16*>(&Ah[qd * 512 + row * 8]);
      a_l[i] = *reinterpret_cast<const frag16*>(&Al[qd * 512 + row * 8]);
    }
#pragma unroll
    for (int j = 0; j < 4; j++) {
      int row = ch * 64 + j * 16 + ln;
      b_h[j] = *reinterpret_cast<const frag16*>(&Bh[qd * 1024 + row * 8]);
    }
#pragma unroll
    for (int i = 0; i < 2; i++)
#pragma unroll
      for (int j = 0; j < 4; j++) {
        acc[i][j] = __builtin_amdgcn_mfma_f32_16x16x32_bf16(a_h[i], b_h[j], acc[i][j], 0, 0, 0);
        acc[i][j] = __builtin_amdgcn_mfma_f32_16x16x32_bf16(a_l[i], b_h[j], acc[i][j], 0, 0, 0);
      }
    __syncthreads();
  }

#pragma unroll
  for (int i = 0; i < 2; i++)
#pragma unroll
    for (int j = 0; j < 4; j++) {
      int jj = j0 + ch * 64 + j * 16 + ln;
      int sel = jj >> 9, hh = (jj >> 6) & 7, d = jj & 63;
      float bv = bias[jj];
#pragma unroll
      for (int r = 0; r < 4; r++) {
        int m = m0 + rh * 32 + i * 16 + qd * 4 + r;
        float val = acc[i][j][r] + bv;
        size_t off = ((size_t)hh * N_TOK + m) * DH + d;
        if (sel == 0) {
          val *= 0.125f;  // fold attention scale (exact pow2)
          unsigned short hv = f2bf(val);
          qhi[off] = hv;
          qlo[off] = f2bf(val - bf2f(hv));
        } else if (sel == 1) {
          khi[off] = f2bf(val);
        } else {
          vhi[off] = f2bf(val);
        }
      }
    }
}

// ---------------------------------------------------------------------------
// Projection GEMM: 64x64 tile, 1-pass bf16 (xattn hi * w_proj hi), fp32 out.
// grid (8, 128) = 1024 blocks = 4/CU.
// ---------------------------------------------------------------------------
__global__ __launch_bounds__(256) void gemm_proj(
    const unsigned short* __restrict__ Ahi, const unsigned short* __restrict__ Bhi,
    const float* __restrict__ bias, float* __restrict__ out) {
  __shared__ short Ah[2048];
  __shared__ short Bh[2048];
  const int tid = threadIdx.x;
  const int j0 = blockIdx.x * 64;
  const int m0 = blockIdx.y * 64;
  const int wave = tid >> 6, lane = tid & 63;
  const int qd = lane >> 4, ln = lane & 15;

  f32x4 acc[4] = {};

  for (int k0 = 0; k0 < C_DIM; k0 += 32) {
#pragma unroll
    for (int s = 0; s < 2; s++) {
      int t = wave * 2 + s;
      if (t < 4) {
        GLL(Ahi + (size_t)(m0 + lane) * C_DIM + k0 + t * 8, &Ah[t * 512 + lane * 8]);
      } else {
        int p = t - 4;
        GLL(Bhi + (size_t)(j0 + lane) * C_DIM + k0 + p * 8, &Bh[p * 512 + lane * 8]);
      }
    }
    __syncthreads();
    frag16 a_h = *reinterpret_cast<const frag16*>(&Ah[qd * 512 + (wave * 16 + ln) * 8]);
#pragma unroll
    for (int j = 0; j < 4; j++) {
      frag16 b_h = *reinterpret_cast<const frag16*>(&Bh[qd * 512 + (j * 16 + ln) * 8]);
      acc[j] = __builtin_amdgcn_mfma_f32_16x16x32_bf16(a_h, b_h, acc[j], 0, 0, 0);
    }
    __syncthreads();
  }

#pragma unroll
  for (int j = 0; j < 4; j++) {
    int jj = j0 + j * 16 + ln;
    float bv = bias[jj];
#pragma unroll
    for (int r = 0; r < 4; r++) {
      int m = m0 + wave * 16 + qd * 4 + r;
      out[(size_t)m * C_DIM + jj] = acc[j][r] + bv;
    }
  }
}

// ---------------------------------------------------------------------------
// fp32 agg path (rank-exact): xbar partials -> qbar -> g -> agg
// ---------------------------------------------------------------------------
__global__ __launch_bounds__(256) void xbar_part(const float* __restrict__ x,
                                                 const int* __restrict__ keyframes,
                                                 float* __restrict__ part) {
  int kk = blockIdx.x, s = blockIdx.y, tid = threadIdx.x;
  int base = keyframes[kk] * TPF + s * 32;
  float a0 = 0.f, a1 = 0.f;
  for (int t = 0; t < 32; t++) {
    a0 += x[(size_t)(base + t) * C_DIM + tid];
    a1 += x[(size_t)(base + t) * C_DIM + tid + 256];
  }
  part[(kk * 16 + s) * C_DIM + tid] = a0;
  part[(kk * 16 + s) * C_DIM + tid + 256] = a1;
}

// qbar[h][kk][d] = W_q . mean(x over keyframe kk) + b_q ; folds xbar reduce.
__global__ __launch_bounds__(256) void qbar_k(const float* __restrict__ w_qkv,
                                              const float* __restrict__ b_qkv,
                                              const float* __restrict__ xbarp,
                                              float* __restrict__ qbar) {
  __shared__ float xs[C_DIM];
  __shared__ float red[256];
  int blk = blockIdx.x, h = blk >> 2, kk = blk & 3, tid = threadIdx.x;
  for (int i = tid; i < C_DIM; i += 256) {
    float a = 0.f;
    for (int s = 0; s < 16; s++) a += xbarp[(kk * 16 + s) * C_DIM + i];
    xs[i] = a * (1.f / 512.f);
  }
  __syncthreads();
  int d = tid & 63, pp = tid >> 6;
  const float* wrow = w_qkv + (size_t)(h * 64 + d) * C_DIM + pp * 128;
  float a = 0.f;
  for (int c = 0; c < 128; c++) a += wrow[c] * xs[pp * 128 + c];
  red[tid] = a;
  __syncthreads();
  if (pp == 0)
    qbar[(h * 4 + kk) * 64 + d] = red[d] + red[64 + d] + red[128 + d] + red[192 + d] +
                                  b_qkv[h * 64 + d];
}

__global__ __launch_bounds__(256) void g_part(const float* __restrict__ w_qkv,
                                              const float* __restrict__ qbar,
                                              float* __restrict__ gp) {
  __shared__ float qs[64];
  int kk = blockIdx.x, hh = blockIdx.y, tid = threadIdx.x;
  if (tid < 64) qs[tid] = qbar[(hh * 4 + kk) * 64 + tid];
  __syncthreads();
  float a0 = 0.f, a1 = 0.f;
  for (int j = 0; j < 64; j++) {
    float qv = qs[j];
    const float* wr = w_qkv + (size_t)(C_DIM + hh * 64 + j) * C_DIM;
    a0 += qv * wr[tid];
    a1 += qv * wr[tid + 256];
  }
  gp[(kk * 8 + hh) * C_DIM + tid] = a0;
  gp[(kk * 8 + hh) * C_DIM + tid + 256] = a1;
}

__global__ void g_reduce(const float* __restrict__ gp, float* __restrict__ g) {
  int kk = blockIdx.x, c = threadIdx.x;
  float a = 0.f;
  for (int s = 0; s < 8; s++) a += gp[(kk * 8 + s) * C_DIM + c];
  g[kk * C_DIM + c] = a;
}

__global__ __launch_bounds__(256) void agg2_kernel(const float* __restrict__ x,
                                                   const float* __restrict__ g,
                                                   float* __restrict__ agg) {
  __shared__ float gs[KCLUST][C_DIM];
  int tid = threadIdx.x;
  for (int i = tid; i < KCLUST * C_DIM; i += 256) gs[i >> 9][i & 511] = g[i];
  __syncthreads();
  int wave = tid >> 6, lane = tid & 63;
  int n = blockIdx.x * 4 + wave;
  const float4* xp = reinterpret_cast<const float4*>(x + (size_t)n * C_DIM);
  float4 xa = xp[lane], xb = xp[lane + 64];
  float a[4];
#pragma unroll
  for (int kk = 0; kk < 4; kk++) {
    const float4* gpv = reinterpret_cast<const float4*>(&gs[kk][0]);
    float4 ga = gpv[lane], gb = gpv[lane + 64];
    a[kk] = xa.x * ga.x + xa.y * ga.y + xa.z * ga.z + xa.w * ga.w +
            xb.x * gb.x + xb.y * gb.y + xb.z * gb.z + xb.w * gb.w;
  }
#pragma unroll
  for (int off = 32; off >= 1; off >>= 1) {
    a[0] += __shfl_xor(a[0], off);
    a[1] += __shfl_xor(a[1], off);
    a[2] += __shfl_xor(a[2], off);
    a[3] += __shfl_xor(a[3], off);
  }
  if (lane == 0) {
    agg[0 * N_TOK + n] = a[0];
    agg[1 * N_TOK + n] = a[1];
    agg[2 * N_TOK + n] = a[2];
    agg[3 * N_TOK + n] = a[3];
  }
}

// ---------------------------------------------------------------------------
// Deterministic top-204 (radix select; ties -> lowest index). Shuffle-reduced.
// ---------------------------------------------------------------------------
__global__ __launch_bounds__(256) void topk_kernel(const float* __restrict__ agg,
                                                   int* __restrict__ topk) {
  __shared__ unsigned sk[N_TOK];
  __shared__ int cnt[4];
  __shared__ int scn[256];
  int kk = blockIdx.x, tid = threadIdx.x;
  int wv = tid >> 6, lane = tid & 63;
  const float* row = agg + (size_t)kk * N_TOK;

  for (int i = tid; i < N_TOK; i += 256) {
    unsigned u = __float_as_uint(row[i]);
    sk[i] = (u & 0x80000000u) ? ~u : (u | 0x80000000u);
  }
  __syncthreads();

  unsigned prefix = 0;
  int remaining = TOPK;
  for (int b = 31; b >= 0; b--) {
    unsigned cand = (prefix | (1u << b)) >> b;
    int c = 0;
    for (int i = tid; i < N_TOK; i += 256) c += ((sk[i] >> b) == cand) ? 1 : 0;
#pragma unroll
    for (int off = 32; off >= 1; off >>= 1) c += __shfl_xor(c, off);
    if (lane == 0) cnt[wv] = c;
    __syncthreads();
    int total = cnt[0] + cnt[1] + cnt[2] + cnt[3];
    __syncthreads();
    if (total >= remaining) prefix |= (1u << b);
    else remaining -= total;
  }
  unsigned kth = prefix;

  int* out_row = topk + kk * TOPK;
  int base = tid * 32;

  int cA = 0;
  for (int i = 0; i < 32; i++) cA += (sk[base + i] > kth) ? 1 : 0;
  scn[tid] = cA;
  __syncthreads();
  for (int s = 1; s < 256; s <<= 1) {
    int add = (tid >= s) ? scn[tid - s] : 0;
    __syncthreads();
    scn[tid] += add;
    __syncthreads();
  }
  int exclA = scn[tid] - cA;
  int G = scn[255];
  __syncthreads();
  int p = exclA;
  for (int i = 0; i < 32; i++)
    if (sk[base + i] > kth) out_row[p++] = base + i;
  __syncthreads();

  int cB = 0;
  for (int i = 0; i < 32; i++) cB += (sk[base + i] == kth) ? 1 : 0;
  scn[tid] = cB;
  __syncthreads();
  for (int s = 1; s < 256; s <<= 1) {
    int add = (tid >= s) ? scn[tid - s] : 0;
    __syncthreads();
    scn[tid] += add;
    __syncthreads();
  }
  int exclB = scn[tid] - cB;
  int pos = G + exclB;
  for (int i = 0; i < 32; i++) {
    if (sk[base + i] == kth) {
      if (pos < TOPK) out_row[pos] = base + i;
      pos++;
    }
  }
}

// ---------------------------------------------------------------------------
// MFMA flash attention, trimmed precision: K/V/P hi-only.
// QK^T: 2 passes (qh*kh + ql*kh). PV: 1 pass. grid (32, KCLUST, NH).
// ---------------------------------------------------------------------------
__global__ __launch_bounds__(256) void flash_mfma(
    const unsigned short* __restrict__ qhi, const unsigned short* __restrict__ qlo,
    const unsigned short* __restrict__ khi, const unsigned short* __restrict__ vhi,
    const int* __restrict__ topk, const int* __restrict__ clusters,
    unsigned short* __restrict__ xahi) {
  __shared__ short Ks[64 * 72];
  __shared__ short Vs[64 * 72];   // transposed: row = d, col = key
  __shared__ short Ps[64 * 72];
  __shared__ int idx[TOPK];
  const int tid = threadIdx.x;
  const int qb = blockIdx.x, kk = blockIdx.y, h = blockIdx.z;
  const int wave = tid >> 6, lane = tid & 63;
  const int ln = lane & 15, qd = lane >> 4;

  for (int i = tid; i < TOPK; i += 256) idx[i] = topk[kk * TOPK + i];

  const int q_local0 = qb * 64;
  const int frame = clusters[kk * 4 + (q_local0 >> 9)];
  const int tokbase = frame * TPF + (q_local0 & 511);

  frag16 qa_h[2], qa_l[2];
  {
    const int tok_m = tokbase + wave * 16 + ln;
    const unsigned short* qr_h = qhi + ((size_t)h * N_TOK + tok_m) * DH;
    const unsigned short* qr_l = qlo + ((size_t)h * N_TOK + tok_m) * DH;
#pragma unroll
    for (int s = 0; s < 2; s++) {
      qa_h[s] = *reinterpret_cast<const frag16*>(qr_h + s * 32 + qd * 8);
      qa_l[s] = *reinterpret_cast<const frag16*>(qr_l + s * 32 + qd * 8);
    }
  }

  f32x4 acc_o[4] = {};
  float lsum[4] = {0.f, 0.f, 0.f, 0.f};

  __syncthreads();  // idx visible

  for (int t0 = 0; t0 < TOPK; t0 += 64) {
    // stage K tile (64 keys x 64 d)
#pragma unroll
    for (int i = 0; i < 2; i++) {
      int u = tid + i * 256;
      int r = u >> 3, oct = u & 7;
      int t = t0 + r;
      if (t > TOPK - 1) t = TOPK - 1;
      *reinterpret_cast<frag16*>(&Ks[r * 72 + oct * 8]) =
          *reinterpret_cast<const frag16*>(khi + ((size_t)h * N_TOK + idx[t]) * DH + oct * 8);
    }
    // stage V transposed (64 d x 64 keys)
#pragma unroll
    for (int i = 0; i < 4; i++) {
      int u = tid + i * 256;
      int t = u >> 4, d4 = (u & 15) * 4;
      int tt = t0 + t;
      if (tt > TOPK - 1) tt = TOPK - 1;
      uint2 w2 = *reinterpret_cast<const uint2*>(
          vhi + ((size_t)h * N_TOK + idx[tt]) * DH + d4);
      Vs[(d4 + 0) * 72 + t] = (short)(w2.x & 0xffff);
      Vs[(d4 + 1) * 72 + t] = (short)(w2.x >> 16);
      Vs[(d4 + 2) * 72 + t] = (short)(w2.y & 0xffff);
      Vs[(d4 + 3) * 72 + t] = (short)(w2.y >> 16);
    }
    __syncthreads();

    // S = Q K^T (2 passes)
    f32x4 sacc[4] = {};
#pragma unroll
    for (int c = 0; c < 4; c++) {
#pragma unroll
      for (int s = 0; s < 2; s++) {
        frag16 bh = *reinterpret_cast<const frag16*>(&Ks[(c * 16 + ln) * 72 + s * 32 + qd * 8]);
        sacc[c] = __builtin_amdgcn_mfma_f32_16x16x32_bf16(qa_h[s], bh, sacc[c], 0, 0, 0);
        sacc[c] = __builtin_amdgcn_mfma_f32_16x16x32_bf16(qa_l[s], bh, sacc[c], 0, 0, 0);
      }
    }

    // P = exp(S), masked at tail; hi-only to LDS (A-layout for PV)
#pragma unroll
    for (int c = 0; c < 4; c++) {
#pragma unroll
      for (int r = 0; r < 4; r++) {
        int tg = t0 + c * 16 + ln;
        float p = (tg < TOPK) ? __expf(sacc[c][r]) : 0.f;
        lsum[r] += p;
        Ps[(wave * 16 + qd * 4 + r) * 72 + c * 16 + ln] = (short)f2bf(p);
      }
    }
    // own-wave LDS RAW: compiler inserts lgkmcnt wait (no barrier needed)

    // O += P V (1 pass)
#pragma unroll
    for (int s = 0; s < 2; s++) {
      frag16 pa = *reinterpret_cast<const frag16*>(&Ps[(wave * 16 + ln) * 72 + s * 32 + qd * 8]);
#pragma unroll
      for (int dt = 0; dt < 4; dt++) {
        frag16 vb = *reinterpret_cast<const frag16*>(&Vs[(dt * 16 + ln) * 72 + s * 32 + qd * 8]);
        acc_o[dt] = __builtin_amdgcn_mfma_f32_16x16x32_bf16(pa, vb, acc_o[dt], 0, 0, 0);
      }
    }
    __syncthreads();  // protect Ks/Vs before next staging
  }

#pragma unroll
  for (int r = 0; r < 4; r++) {
    float l = lsum[r];
    l += __shfl_xor(l, 1);
    l += __shfl_xor(l, 2);
    l += __shfl_xor(l, 4);
    l += __shfl_xor(l, 8);
    lsum[r] = 1.f / l;
  }

#pragma unroll
  for (int dt = 0; dt < 4; dt++)
#pragma unroll
    for (int r = 0; r < 4; r++) {
      float val = acc_o[dt][r] * lsum[r];
      int tok = tokbase + wave * 16 + qd * 4 + r;
      xahi[(size_t)tok * C_DIM + h * DH + dt * 16 + ln] = f2bf(val);
    }
}

// ---------------------------------------------------------------------------
extern "C" void kernel_launch(void* const* d_in, const int* in_sizes, int n_in,
                              void* d_out, int out_size, void* d_ws, size_t ws_size,
                              hipStream_t stream) {
  const float* x = (const float*)d_in[0];
  const float* w_qkv = (const float*)d_in[1];
  const float* b_qkv = (const float*)d_in[2];
  const float* w_proj = (const float*)d_in[3];
  const float* b_proj = (const float*)d_in[4];
  const int* keyframes = (const int*)d_in[5];
  const int* clusters = (const int*)d_in[6];
  float* out = (float*)d_out;
  float* ws = (float*)d_ws;

  unsigned short* xhi = (unsigned short*)(ws + WS_XHI);
  unsigned short* xlo = (unsigned short*)(ws + WS_XLO);
  unsigned short* wqh = (unsigned short*)(ws + WS_WQH);
  unsigned short* wph = (unsigned short*)(ws + WS_WPH);
  unsigned short* qhi = (unsigned short*)(ws + WS_QHI);
  unsigned short* qlo = (unsigned short*)(ws + WS_QLO);
  unsigned short* khi = (unsigned short*)(ws + WS_KHI);
  unsigned short* vhi = (unsigned short*)(ws + WS_VHI);
  unsigned short* xahi = (unsigned short*)(ws + WS_XAHI);
  float* xbarp = ws + WS_XBARP;
  float* qbar = ws + WS_QBAR;
  float* gpart = ws + WS_GPART;
  float* g = ws + WS_G;
  float* agg = ws + WS_AGG;
  int* topk = (int*)(ws + WS_TOPK);

  // conversions: x split (hi+lo), weights hi-only
  cvt_split<<<4096, 256, 0, stream>>>(x, xhi, xlo, 1048576);
  cvt_hi<<<768, 256, 0, stream>>>(w_qkv, wqh, 196608);
  cvt_hi<<<256, 256, 0, stream>>>(w_proj, wph, 65536);

  // QKV GEMM (2-pass) -> q hi/lo (scaled), k hi, v hi
  gemm_qkv<<<dim3(12, 128), 256, 0, stream>>>(xhi, xlo, wqh, b_qkv,
                                              qhi, qlo, khi, vhi);

  // fp32 agg path (rank-exact): xbar partials -> qbar -> g -> agg -> topk
  xbar_part<<<dim3(4, 16), 256, 0, stream>>>(x, keyframes, xbarp);
  qbar_k<<<32, 256, 0, stream>>>(w_qkv, b_qkv, xbarp, qbar);
  g_part<<<dim3(4, 8), 256, 0, stream>>>(w_qkv, qbar, gpart);
  g_reduce<<<4, 512, 0, stream>>>(gpart, g);
  agg2_kernel<<<2048, 256, 0, stream>>>(x, g, agg);
  topk_kernel<<<4, 256, 0, stream>>>(agg, topk);

  // fused MFMA attention (clusters cover all tokens)
  flash_mfma<<<dim3(MPC / 64, KCLUST, NH), 256, 0, stream>>>(
      qhi, qlo, khi, vhi, topk, clusters, xahi);

  // projection GEMM (1-pass bf16) -> d_out
  gemm_proj<<<dim3(8, 128), 256, 0, stream>>>(xahi, wph, b_proj, out);
}